// Round 13
// baseline (212.363 us; speedup 1.0000x reference)
//
#include <hip/hip_runtime.h>
#include <hip/hip_bf16.h>
#include <cstdint>

#define T_TOK 8192
#define H_DIM 2048
#define N_EXP 8
#define FLAGBIT 0x80000000u

typedef __attribute__((ext_vector_type(4))) float f32x4;
typedef __attribute__((ext_vector_type(8))) short bf16x8;

__device__ __forceinline__ unsigned short f2bf(float f) {
  unsigned int u = __builtin_bit_cast(unsigned int, f);
  u += 0x7fffu + ((u >> 16) & 1u);  // RNE
  return (unsigned short)(u >> 16);
}

#define GLL(SRC, DST) __builtin_amdgcn_global_load_lds( \
    (const __attribute__((address_space(1))) void*)(SRC), \
    (__attribute__((address_space(3))) void*)(DST), 16, 0, 0)

// ---- conv: W f32->bf16 (r12: forced 16-deep load pipeline) ----
__global__ __launch_bounds__(256, 2) void k_conv(const float* __restrict__ we,
                                                 unsigned short* __restrict__ wb) {
  const size_t tix = ((size_t)blockIdx.x * 256 + threadIdx.x) * 8;
  const size_t stride = (size_t)2048 * 256 * 8;
  f32x4 v[16];
#pragma unroll
  for (int it = 0; it < 8; ++it) {
    v[2 * it]     = *reinterpret_cast<const f32x4*>(we + tix + (size_t)it * stride);
    v[2 * it + 1] = *reinterpret_cast<const f32x4*>(we + tix + (size_t)it * stride + 4);
  }
#pragma unroll
  for (int q = 0; q < 16; ++q) asm volatile("" : "+v"(v[q]));
#pragma unroll
  for (int it = 0; it < 8; ++it) {
    union { unsigned short h[8]; uint4 u; } r;
#pragma unroll
    for (int q = 0; q < 4; ++q) {
      r.h[q]     = f2bf(v[2 * it][q]);
      r.h[4 + q] = f2bf(v[2 * it + 1][q]);
    }
    *reinterpret_cast<uint4*>(wb + tix + (size_t)it * stride) = r.u;
  }
}

// ---- router: wr in LDS, 4 tok/wave, atomic-free (r12) ----
__global__ __launch_bounds__(256) void k_router(const float* __restrict__ x,
    const float* __restrict__ wr, unsigned short* __restrict__ xb,
    int* __restrict__ idx)
{
  __shared__ float swr[N_EXP * H_DIM];  // 64 KB
#pragma unroll
  for (int i = 0; i < 16; ++i) {
    const int o = (threadIdx.x + i * 256) * 4;
    *reinterpret_cast<float4*>(&swr[o]) = *reinterpret_cast<const float4*>(&wr[o]);
  }
  __syncthreads();
  const int wv = threadIdx.x >> 6, lane = threadIdx.x & 63;
  const int t0 = (blockIdx.x * 4 + wv) * 4;
  float acc[4][N_EXP];
#pragma unroll
  for (int tt = 0; tt < 4; ++tt)
#pragma unroll
    for (int e = 0; e < N_EXP; ++e) acc[tt][e] = 0.f;
#pragma unroll
  for (int c = 0; c < H_DIM / 256; ++c) {
    const int h = c * 256 + lane * 4;
    float4 wvv[N_EXP];
#pragma unroll
    for (int e = 0; e < N_EXP; ++e)
      wvv[e] = *reinterpret_cast<const float4*>(&swr[e * H_DIM + h]);
#pragma unroll
    for (int tt = 0; tt < 4; ++tt) {
      const float4 xv = *reinterpret_cast<const float4*>(x + (size_t)(t0 + tt) * H_DIM + h);
      ushort4 bv;
      bv.x = f2bf(xv.x); bv.y = f2bf(xv.y); bv.z = f2bf(xv.z); bv.w = f2bf(xv.w);
      *reinterpret_cast<ushort4*>(xb + (size_t)(t0 + tt) * H_DIM + h) = bv;
#pragma unroll
      for (int e = 0; e < N_EXP; ++e) {
        acc[tt][e] = fmaf(xv.x, wvv[e].x, acc[tt][e]);
        acc[tt][e] = fmaf(xv.y, wvv[e].y, acc[tt][e]);
        acc[tt][e] = fmaf(xv.z, wvv[e].z, acc[tt][e]);
        acc[tt][e] = fmaf(xv.w, wvv[e].w, acc[tt][e]);
      }
    }
  }
#pragma unroll
  for (int off = 32; off >= 1; off >>= 1)
#pragma unroll
    for (int tt = 0; tt < 4; ++tt)
#pragma unroll
      for (int e = 0; e < N_EXP; ++e) acc[tt][e] += __shfl_xor(acc[tt][e], off, 64);
  if (lane == 0) {
#pragma unroll
    for (int tt = 0; tt < 4; ++tt) {
      float best = acc[tt][0]; int be = 0;
#pragma unroll
      for (int e = 1; e < N_EXP; ++e) if (acc[tt][e] > best) { best = acc[tt][e]; be = e; }
      idx[t0 + tt] = be;
    }
  }
}

// ---- fused sort: hist + scan + stable place + maps, one block of 1024 (r11) ----
__global__ __launch_bounds__(1024) void k_sort(const int* __restrict__ idx,
    int* __restrict__ tlist, int* __restrict__ estar, int* __restrict__ mlo,
    int* __restrict__ mhi, int* __restrict__ rpos, int* __restrict__ rtile,
    int* __restrict__ rtc)
{
  __shared__ int wc[N_EXP][128];
  __shared__ int wbase[N_EXP][128];
  __shared__ int sTot[N_EXP];
  __shared__ int off[N_EXP + 1];
  __shared__ int sE[32], sCnt[N_EXP], sBase[N_EXP];
  const int tid = threadIdx.x, w = tid >> 6, l = tid & 63;
  int myE[8];
#pragma unroll
  for (int j = 0; j < 8; ++j) {
    myE[j] = idx[j * 1024 + tid];
#pragma unroll
    for (int e = 0; e < N_EXP; ++e) {
      const unsigned long long bm = __ballot(myE[j] == e);
      if (l == e) wc[e][j * 16 + w] = __popcll(bm);
    }
  }
  __syncthreads();
  if (tid < N_EXP) {
    int s = 0;
    for (int k = 0; k < 128; ++k) { wbase[tid][k] = s; s += wc[tid][k]; }
    sTot[tid] = s;
  }
  __syncthreads();
  if (tid == 0) {
    off[0] = 0;
    for (int e = 0; e < N_EXP; ++e) off[e + 1] = off[e] + sTot[e];
  }
  __syncthreads();
#pragma unroll
  for (int j = 0; j < 8; ++j) {
    int rank = 0;
#pragma unroll
    for (int e = 0; e < N_EXP; ++e) {
      const unsigned long long bm = __ballot(myE[j] == e);
      if (myE[j] == e) rank = __popcll(bm & ((1ull << l) - 1ull));
    }
    tlist[off[myE[j]] + wbase[myE[j]][j * 16 + w] + rank] = j * 1024 + tid;
  }
  if (tid < 32) {
    const int lo = tid * 256, hi = lo + 256;
    int bl = -1, bE = 0, bLo = 0, bHi = 0;
#pragma unroll
    for (int e = 0; e < N_EXP; ++e) {
      const int a = off[e] > lo ? off[e] : lo;
      const int b = off[e + 1] < hi ? off[e + 1] : hi;
      if (b - a > bl) { bl = b - a; bE = e; bLo = a - lo; bHi = b - lo; }
    }
    sE[tid] = bE; estar[tid] = bE; mlo[tid] = bLo; mhi[tid] = bHi;
  }
  __syncthreads();
  if (tid < N_EXP) {
    int cnt = 0;
    for (int t = 0; t < 32; ++t) {
      if (sE[t] == tid) continue;
      const int lo = t * 256, hi = lo + 256;
      const int a = off[tid] > lo ? off[tid] : lo;
      const int b = off[tid + 1] < hi ? off[tid + 1] : hi;
      if (b > a) cnt += b - a;
    }
    sCnt[tid] = cnt;
  }
  __syncthreads();
  if (tid == 0) {
    int base = 0, ntile = 0;
    for (int e = 0; e < N_EXP; ++e) {
      sBase[e] = base;
      const int pt = (sCnt[e] + 127) >> 7;
      for (int k = 0; k < pt; ++k) rtile[ntile++] = e;
      base += pt << 7;
    }
    *rtc = ntile;
  }
  __syncthreads();
  if (tid < N_EXP && sCnt[tid] > 0) {
    int ptr = sBase[tid], firstp = -1;
    for (int t = 0; t < 32; ++t) {
      if (sE[t] == tid) continue;
      const int lo = t * 256, hi = lo + 256;
      const int a = off[tid] > lo ? off[tid] : lo;
      const int b = off[tid + 1] < hi ? off[tid + 1] : hi;
      for (int p = a; p < b; ++p) { if (firstp < 0) firstp = p; rpos[ptr++] = p; }
    }
    const int end = sBase[tid] + (((sCnt[tid] + 127) >> 7) << 7);
    for (; ptr < end; ++ptr) rpos[ptr] = (int)((unsigned)firstp | FLAGBIT);
  }
}

// ---- r9 8-phase gphase (bf16 wb, GLL both operands, counted vmcnt) ----
template<int Q, bool LOADB, bool VMC>
__device__ __forceinline__ void gphase(const char* LP,
    __attribute__((address_space(3))) char* LDS3,
    int rdBase, int aRowOff, int bRowOff, int ch0, int ch1,
    bf16x8 (&bfr)[8], f32x4 (&acc)[8][4],
    const unsigned short* s0, const unsigned short* s1, int d0, int d1)
{
  if constexpr (LOADB) {
#pragma unroll
    for (int nf = 0; nf < 4; ++nf) {
      bfr[nf * 2 + 0] = *reinterpret_cast<const bf16x8*>(LP + rdBase + 32768 + bRowOff + nf * 2048 + ch0);
      bfr[nf * 2 + 1] = *reinterpret_cast<const bf16x8*>(LP + rdBase + 32768 + bRowOff + nf * 2048 + ch1);
    }
  }
  bf16x8 af[2][2];
#pragma unroll
  for (int m = 0; m < 2; ++m) {
    af[m][0] = *reinterpret_cast<const bf16x8*>(LP + rdBase + aRowOff + (2 * Q + m) * 2048 + ch0);
    af[m][1] = *reinterpret_cast<const bf16x8*>(LP + rdBase + aRowOff + (2 * Q + m) * 2048 + ch1);
  }
  GLL(s0, LDS3 + d0);
  GLL(s1, LDS3 + d1);
  __builtin_amdgcn_sched_barrier(0);
  __builtin_amdgcn_s_barrier();
  __builtin_amdgcn_sched_barrier(0);
  __builtin_amdgcn_s_setprio(1);
#pragma unroll
  for (int ks = 0; ks < 2; ++ks)
#pragma unroll
    for (int m = 0; m < 2; ++m)
#pragma unroll
      for (int nf = 0; nf < 4; ++nf)
        acc[2 * Q + m][nf] = __builtin_amdgcn_mfma_f32_16x16x32_bf16(af[m][ks], bfr[nf * 2 + ks], acc[2 * Q + m][nf], 0, 0, 0);
  __builtin_amdgcn_s_setprio(0);
  if constexpr (VMC) asm volatile("s_waitcnt vmcnt(4)" ::: "memory");
  __builtin_amdgcn_sched_barrier(0);
  __builtin_amdgcn_s_barrier();
  __builtin_amdgcn_sched_barrier(0);
}

// ---- main grouped GEMM (r9): 256 blocks, minority cells zeroed (repair adds) ----
__global__ __launch_bounds__(512, 2) void k_gemm(const unsigned short* __restrict__ xb,
    const unsigned short* __restrict__ wb, const int* __restrict__ tlist,
    const int* __restrict__ estar, const int* __restrict__ mlo, const int* __restrict__ mhi,
    float* __restrict__ out)
{
  __shared__ short lds[65536];  // 128 KiB: buf0 @0, buf1 @65536
  const int bid = blockIdx.x;
  const int mt = (bid & 7) * 4 + ((bid >> 3) & 3);  // XCD-locality map
  const int nt = bid >> 5;
  const int m0 = mt * 256, f0 = nt * 256;
  const int e = estar[mt], mLo = mlo[mt], mHi = mhi[mt];
  const int tid = threadIdx.x;
  const int l = tid & 63, wv = tid >> 6;
  const int wm = wv >> 2, wn = wv & 3;
  const int l16 = l & 15, g = l >> 4;
  const char* LP = (const char*)lds;
  auto* LDS3 = (__attribute__((address_space(3))) char*)lds;

  const int sw = l16 & 7;
  const int ch0 = ((0 + g) ^ sw) << 4;
  const int ch1 = ((4 + g) ^ sw) << 4;
  const int aRowOff = (wm * 128 + l16) * 128;
  const int bRowOff = (wn * 64 + l16) * 128;

  const int csrc = ((l & 7) ^ ((l >> 3) & 7)) * 8;
  const int srow = l >> 3;
  const unsigned short* aP[2][2];
  const unsigned short* bP[2][2];
  const unsigned short* wpan = wb + (size_t)e * H_DIM * H_DIM;
#pragma unroll
  for (int h = 0; h < 2; ++h)
#pragma unroll
    for (int j = 0; j < 2; ++j) {
      const int tok = tlist[m0 + h * 128 + (wv * 2 + j) * 8 + srow];
      aP[h][j] = xb + (size_t)tok * H_DIM + csrc;
      bP[h][j] = wpan + (size_t)(f0 + h * 128 + (wv * 2 + j) * 8 + srow) * H_DIM + csrc;
    }
  const int sl0 = wv * 2048, sl1 = wv * 2048 + 1024;

  f32x4 acc[8][4];
#pragma unroll
  for (int mf = 0; mf < 8; ++mf)
#pragma unroll
    for (int nf = 0; nf < 4; ++nf) acc[mf][nf] = (f32x4){0.f, 0.f, 0.f, 0.f};
  bf16x8 bfr[8];

  GLL(aP[0][0], LDS3 + 0 + sl0);      GLL(aP[0][1], LDS3 + 0 + sl1);
  GLL(aP[1][0], LDS3 + 16384 + sl0);  GLL(aP[1][1], LDS3 + 16384 + sl1);
  GLL(bP[0][0], LDS3 + 32768 + sl0);  GLL(bP[0][1], LDS3 + 32768 + sl1);
  GLL(bP[1][0], LDS3 + 49152 + sl0);  GLL(bP[1][1], LDS3 + 49152 + sl1);
  GLL(bP[0][0] + 64, LDS3 + 65536 + 32768 + sl0);  GLL(bP[0][1] + 64, LDS3 + 65536 + 32768 + sl1);
  GLL(bP[1][0] + 64, LDS3 + 65536 + 49152 + sl0);  GLL(bP[1][1] + 64, LDS3 + 65536 + 49152 + sl1);
  asm volatile("s_waitcnt vmcnt(4)" ::: "memory");
  __builtin_amdgcn_sched_barrier(0);
  __builtin_amdgcn_s_barrier();
  __builtin_amdgcn_sched_barrier(0);

  for (int i = 0; i < 16; ++i) {
    const int kk1 = ((2 * i + 1) << 6) & (H_DIM - 1);
    const int kk2 = ((2 * i + 2) << 6) & (H_DIM - 1);
    const int kk3 = ((2 * i + 3) << 6) & (H_DIM - 1);
    gphase<0, true , false>(LP, LDS3, 0, aRowOff, bRowOff, ch0, ch1, bfr, acc,
        aP[0][0] + kk1, aP[0][1] + kk1, 65536 + 0 + sl0, 65536 + 0 + sl1);
    gphase<1, false, false>(LP, LDS3, 0, aRowOff, bRowOff, ch0, ch1, bfr, acc,
        aP[1][0] + kk1, aP[1][1] + kk1, 65536 + 16384 + sl0, 65536 + 16384 + sl1);
    gphase<2, false, false>(LP, LDS3, 0, aRowOff, bRowOff, ch0, ch1, bfr, acc,
        bP[0][0] + kk2, bP[0][1] + kk2, 0 + 32768 + sl0, 0 + 32768 + sl1);
    gphase<3, false, true >(LP, LDS3, 0, aRowOff, bRowOff, ch0, ch1, bfr, acc,
        bP[1][0] + kk2, bP[1][1] + kk2, 0 + 49152 + sl0, 0 + 49152 + sl1);
    gphase<0, true , false>(LP, LDS3, 65536, aRowOff, bRowOff, ch0, ch1, bfr, acc,
        aP[0][0] + kk2, aP[0][1] + kk2, 0 + 0 + sl0, 0 + 0 + sl1);
    gphase<1, false, false>(LP, LDS3, 65536, aRowOff, bRowOff, ch0, ch1, bfr, acc,
        aP[1][0] + kk2, aP[1][1] + kk2, 0 + 16384 + sl0, 0 + 16384 + sl1);
    gphase<2, false, false>(LP, LDS3, 65536, aRowOff, bRowOff, ch0, ch1, bfr, acc,
        bP[0][0] + kk3, bP[0][1] + kk3, 65536 + 32768 + sl0, 65536 + 32768 + sl1);
    gphase<3, false, true >(LP, LDS3, 65536, aRowOff, bRowOff, ch0, ch1, bfr, acc,
        bP[1][0] + kk3, bP[1][1] + kk3, 65536 + 49152 + sl0, 65536 + 49152 + sl1);
  }

  // epilogue: majority rows get results; minority rows zeroed (repair atomicAdds)
#pragma unroll
  for (int mf = 0; mf < 8; ++mf) {
#pragma unroll
    for (int r = 0; r < 4; ++r) {
      const int row = wm * 128 + mf * 16 + g * 4 + r;
      const int t = tlist[m0 + row];
      const bool own = (row >= mLo) && (row < mHi);
      float* op = out + (size_t)t * H_DIM + f0 + wn * 64 + l16;
#pragma unroll
      for (int nf = 0; nf < 4; ++nf) op[nf * 16] = own ? acc[mf][nf][r] : 0.f;
    }
  }
}

// ---- repair (r9): minority rows, split-K(4) atomicAdd onto zeros; small LDS ----
__global__ __launch_bounds__(256, 2) void k_repair(const unsigned short* __restrict__ xb,
    const unsigned short* __restrict__ wb, const int* __restrict__ tlist,
    const int* __restrict__ rpos, const int* __restrict__ rtile, const int* __restrict__ rtc,
    float* __restrict__ out)
{
  const int bx = blockIdx.x;
  if (bx >= *rtc) return;
  __shared__ short lds[24576];  // A 16KB @0 (128x128B), B 32KB @16384 (256x128B)
  const int f0 = blockIdx.y * 256, kc = blockIdx.z;
  const int e = rtile[bx];
  const int tid = threadIdx.x, l = tid & 63, wv = tid >> 6;
  const int wm = wv >> 1, wn = wv & 1;
  const int l16 = l & 15, g = l >> 4;
  const char* LP = (const char*)lds;
  auto* LDS3 = (__attribute__((address_space(3))) char*)lds;
  const int sw = l16 & 7;
  const int ch0 = ((0 + g) ^ sw) << 4, ch1 = ((4 + g) ^ sw) << 4;
  const int csrc = ((l & 7) ^ ((l >> 3) & 7)) * 8;
  const int srow = l >> 3;

  const unsigned short* aS[4];
#pragma unroll
  for (int j = 0; j < 4; ++j) {
    const int ent = rpos[bx * 128 + (wv * 4 + j) * 8 + srow];
    const int tok = tlist[ent & 0x7fffffff];
    aS[j] = xb + (size_t)tok * H_DIM + csrc;
  }
  const unsigned short* bS[8];
#pragma unroll
  for (int j = 0; j < 8; ++j)
    bS[j] = wb + (size_t)e * H_DIM * H_DIM + (size_t)(f0 + (wv * 8 + j) * 8 + srow) * H_DIM + csrc;

  f32x4 acc[4][8];
#pragma unroll
  for (int mf = 0; mf < 4; ++mf)
#pragma unroll
    for (int nf = 0; nf < 8; ++nf) acc[mf][nf] = (f32x4){0.f, 0.f, 0.f, 0.f};

  for (int it = 0; it < 8; ++it) {
    const int kk = kc * 512 + it * 64;
    __syncthreads();
#pragma unroll
    for (int j = 0; j < 4; ++j) GLL(aS[j] + kk, LDS3 + (wv * 4 + j) * 1024);
#pragma unroll
    for (int j = 0; j < 8; ++j) GLL(bS[j] + kk, LDS3 + 16384 + (wv * 8 + j) * 1024);
    __syncthreads();
    bf16x8 af[4][2];
#pragma unroll
    for (int mf = 0; mf < 4; ++mf) {
      af[mf][0] = *reinterpret_cast<const bf16x8*>(LP + (wm * 64 + mf * 16 + l16) * 128 + ch0);
      af[mf][1] = *reinterpret_cast<const bf16x8*>(LP + (wm * 64 + mf * 16 + l16) * 128 + ch1);
    }
#pragma unroll
    for (int nf = 0; nf < 8; ++nf) {
      const bf16x8 b0 = *reinterpret_cast<const bf16x8*>(LP + 16384 + (wn * 128 + nf * 16 + l16) * 128 + ch0);
      const bf16x8 b1 = *reinterpret_cast<const bf16x8*>(LP + 16384 + (wn * 128 + nf * 16 + l16) * 128 + ch1);
#pragma unroll
      for (int mf = 0; mf < 4; ++mf) {
        acc[mf][nf] = __builtin_amdgcn_mfma_f32_16x16x32_bf16(af[mf][0], b0, acc[mf][nf], 0, 0, 0);
        acc[mf][nf] = __builtin_amdgcn_mfma_f32_16x16x32_bf16(af[mf][1], b1, acc[mf][nf], 0, 0, 0);
      }
    }
  }
#pragma unroll
  for (int mf = 0; mf < 4; ++mf) {
#pragma unroll
    for (int r = 0; r < 4; ++r) {
      const int row = wm * 64 + mf * 16 + g * 4 + r;
      const int ent = rpos[bx * 128 + row];
      if (!((unsigned)ent & FLAGBIT)) {
        const int tok = tlist[ent];
        float* op = out + (size_t)tok * H_DIM + f0 + wn * 128 + l16;
#pragma unroll
        for (int nf = 0; nf < 8; ++nf) atomicAdd(op + nf * 16, acc[mf][nf][r]);
      }
    }
  }
}

extern "C" void kernel_launch(void* const* d_in, const int* in_sizes, int n_in,
                              void* d_out, int out_size, void* d_ws, size_t ws_size,
                              hipStream_t stream) {
  const float* x  = (const float*)d_in[0];
  const float* wr = (const float*)d_in[1];
  const float* we = (const float*)d_in[2];
  float* out = (float*)d_out;

  char* p = (char*)d_ws;
  unsigned short* xb = (unsigned short*)p; p += (size_t)T_TOK * H_DIM * 2;          // 32 MB
  unsigned short* wb = (unsigned short*)p; p += (size_t)N_EXP * H_DIM * H_DIM * 2;  // 64 MB
  int* idx    = (int*)p; p += T_TOK * 4;
  int* tlist  = (int*)p; p += T_TOK * 4;
  int* rpos   = (int*)p; p += T_TOK * 4;
  int* estar  = (int*)p; p += 32 * 4;
  int* mlo    = (int*)p; p += 32 * 4;
  int* mhi    = (int*)p; p += 32 * 4;
  int* rtile  = (int*)p; p += 64 * 4;
  int* rtc    = (int*)p; p += 64;

  k_conv<<<2048, 256, 0, stream>>>(we, wb);
  k_router<<<512, 256, 0, stream>>>(x, wr, xb, idx);
  k_sort<<<1, 1024, 0, stream>>>(idx, tlist, estar, mlo, mhi, rpos, rtile, rtc);
  k_gemm<<<256, 512, 0, stream>>>(xb, wb, tlist, estar, mlo, mhi, out);
  k_repair<<<dim3(64, 8, 4), 256, 0, stream>>>(xb, wb, tlist, rpos, rtile, rtc, out);
}

// Round 14
// 210.310 us; speedup vs baseline: 1.0098x; 1.0098x over previous
//
#include <hip/hip_runtime.h>
#include <hip/hip_bf16.h>
#include <cstdint>

#define T_TOK 8192
#define H_DIM 2048
#define N_EXP 8
#define FLAGBIT 0x80000000u

typedef __attribute__((ext_vector_type(4))) float f32x4;
typedef __attribute__((ext_vector_type(16))) float f32x16;
typedef __attribute__((ext_vector_type(8))) short bf16x8;

__device__ __forceinline__ unsigned short f2bf(float f) {
  unsigned int u = __builtin_bit_cast(unsigned int, f);
  u += 0x7fffu + ((u >> 16) & 1u);  // RNE
  return (unsigned short)(u >> 16);
}

#define GLL(SRC, DST) __builtin_amdgcn_global_load_lds( \
    (const __attribute__((address_space(1))) void*)(SRC), \
    (__attribute__((address_space(3))) void*)(DST), 16, 0, 0)

// ---- conv: W f32->bf16 (r12: forced 16-deep load pipeline) ----
__global__ __launch_bounds__(256, 2) void k_conv(const float* __restrict__ we,
                                                 unsigned short* __restrict__ wb) {
  const size_t tix = ((size_t)blockIdx.x * 256 + threadIdx.x) * 8;
  const size_t stride = (size_t)2048 * 256 * 8;
  f32x4 v[16];
#pragma unroll
  for (int it = 0; it < 8; ++it) {
    v[2 * it]     = *reinterpret_cast<const f32x4*>(we + tix + (size_t)it * stride);
    v[2 * it + 1] = *reinterpret_cast<const f32x4*>(we + tix + (size_t)it * stride + 4);
  }
#pragma unroll
  for (int q = 0; q < 16; ++q) asm volatile("" : "+v"(v[q]));
#pragma unroll
  for (int it = 0; it < 8; ++it) {
    union { unsigned short h[8]; uint4 u; } r;
#pragma unroll
    for (int q = 0; q < 4; ++q) {
      r.h[q]     = f2bf(v[2 * it][q]);
      r.h[4 + q] = f2bf(v[2 * it + 1][q]);
    }
    *reinterpret_cast<uint4*>(wb + tix + (size_t)it * stride) = r.u;
  }
}

// ---- router: wr in LDS, 4 tok/wave, atomic-free (r12) ----
__global__ __launch_bounds__(256) void k_router(const float* __restrict__ x,
    const float* __restrict__ wr, unsigned short* __restrict__ xb,
    int* __restrict__ idx)
{
  __shared__ float swr[N_EXP * H_DIM];  // 64 KB
#pragma unroll
  for (int i = 0; i < 16; ++i) {
    const int o = (threadIdx.x + i * 256) * 4;
    *reinterpret_cast<float4*>(&swr[o]) = *reinterpret_cast<const float4*>(&wr[o]);
  }
  __syncthreads();
  const int wv = threadIdx.x >> 6, lane = threadIdx.x & 63;
  const int t0 = (blockIdx.x * 4 + wv) * 4;
  float acc[4][N_EXP];
#pragma unroll
  for (int tt = 0; tt < 4; ++tt)
#pragma unroll
    for (int e = 0; e < N_EXP; ++e) acc[tt][e] = 0.f;
#pragma unroll
  for (int c = 0; c < H_DIM / 256; ++c) {
    const int h = c * 256 + lane * 4;
    float4 wvv[N_EXP];
#pragma unroll
    for (int e = 0; e < N_EXP; ++e)
      wvv[e] = *reinterpret_cast<const float4*>(&swr[e * H_DIM + h]);
#pragma unroll
    for (int tt = 0; tt < 4; ++tt) {
      const float4 xv = *reinterpret_cast<const float4*>(x + (size_t)(t0 + tt) * H_DIM + h);
      ushort4 bv;
      bv.x = f2bf(xv.x); bv.y = f2bf(xv.y); bv.z = f2bf(xv.z); bv.w = f2bf(xv.w);
      *reinterpret_cast<ushort4*>(xb + (size_t)(t0 + tt) * H_DIM + h) = bv;
#pragma unroll
      for (int e = 0; e < N_EXP; ++e) {
        acc[tt][e] = fmaf(xv.x, wvv[e].x, acc[tt][e]);
        acc[tt][e] = fmaf(xv.y, wvv[e].y, acc[tt][e]);
        acc[tt][e] = fmaf(xv.z, wvv[e].z, acc[tt][e]);
        acc[tt][e] = fmaf(xv.w, wvv[e].w, acc[tt][e]);
      }
    }
  }
#pragma unroll
  for (int off = 32; off >= 1; off >>= 1)
#pragma unroll
    for (int tt = 0; tt < 4; ++tt)
#pragma unroll
      for (int e = 0; e < N_EXP; ++e) acc[tt][e] += __shfl_xor(acc[tt][e], off, 64);
  if (lane == 0) {
#pragma unroll
    for (int tt = 0; tt < 4; ++tt) {
      float best = acc[tt][0]; int be = 0;
#pragma unroll
      for (int e = 1; e < N_EXP; ++e) if (acc[tt][e] > best) { best = acc[tt][e]; be = e; }
      idx[t0 + tt] = be;
    }
  }
}

// ---- fused sort (r11) ----
__global__ __launch_bounds__(1024) void k_sort(const int* __restrict__ idx,
    int* __restrict__ tlist, int* __restrict__ estar, int* __restrict__ mlo,
    int* __restrict__ mhi, int* __restrict__ rpos, int* __restrict__ rtile,
    int* __restrict__ rtc)
{
  __shared__ int wc[N_EXP][128];
  __shared__ int wbase[N_EXP][128];
  __shared__ int sTot[N_EXP];
  __shared__ int off[N_EXP + 1];
  __shared__ int sE[32], sCnt[N_EXP], sBase[N_EXP];
  const int tid = threadIdx.x, w = tid >> 6, l = tid & 63;
  int myE[8];
#pragma unroll
  for (int j = 0; j < 8; ++j) {
    myE[j] = idx[j * 1024 + tid];
#pragma unroll
    for (int e = 0; e < N_EXP; ++e) {
      const unsigned long long bm = __ballot(myE[j] == e);
      if (l == e) wc[e][j * 16 + w] = __popcll(bm);
    }
  }
  __syncthreads();
  if (tid < N_EXP) {
    int s = 0;
    for (int k = 0; k < 128; ++k) { wbase[tid][k] = s; s += wc[tid][k]; }
    sTot[tid] = s;
  }
  __syncthreads();
  if (tid == 0) {
    off[0] = 0;
    for (int e = 0; e < N_EXP; ++e) off[e + 1] = off[e] + sTot[e];
  }
  __syncthreads();
#pragma unroll
  for (int j = 0; j < 8; ++j) {
    int rank = 0;
#pragma unroll
    for (int e = 0; e < N_EXP; ++e) {
      const unsigned long long bm = __ballot(myE[j] == e);
      if (myE[j] == e) rank = __popcll(bm & ((1ull << l) - 1ull));
    }
    tlist[off[myE[j]] + wbase[myE[j]][j * 16 + w] + rank] = j * 1024 + tid;
  }
  if (tid < 32) {
    const int lo = tid * 256, hi = lo + 256;
    int bl = -1, bE = 0, bLo = 0, bHi = 0;
#pragma unroll
    for (int e = 0; e < N_EXP; ++e) {
      const int a = off[e] > lo ? off[e] : lo;
      const int b = off[e + 1] < hi ? off[e + 1] : hi;
      if (b - a > bl) { bl = b - a; bE = e; bLo = a - lo; bHi = b - lo; }
    }
    sE[tid] = bE; estar[tid] = bE; mlo[tid] = bLo; mhi[tid] = bHi;
  }
  __syncthreads();
  if (tid < N_EXP) {
    int cnt = 0;
    for (int t = 0; t < 32; ++t) {
      if (sE[t] == tid) continue;
      const int lo = t * 256, hi = lo + 256;
      const int a = off[tid] > lo ? off[tid] : lo;
      const int b = off[tid + 1] < hi ? off[tid + 1] : hi;
      if (b > a) cnt += b - a;
    }
    sCnt[tid] = cnt;
  }
  __syncthreads();
  if (tid == 0) {
    int base = 0, ntile = 0;
    for (int e = 0; e < N_EXP; ++e) {
      sBase[e] = base;
      const int pt = (sCnt[e] + 127) >> 7;
      for (int k = 0; k < pt; ++k) rtile[ntile++] = e;
      base += pt << 7;
    }
    *rtc = ntile;
  }
  __syncthreads();
  if (tid < N_EXP && sCnt[tid] > 0) {
    int ptr = sBase[tid], firstp = -1;
    for (int t = 0; t < 32; ++t) {
      if (sE[t] == tid) continue;
      const int lo = t * 256, hi = lo + 256;
      const int a = off[tid] > lo ? off[tid] : lo;
      const int b = off[tid + 1] < hi ? off[tid + 1] : hi;
      for (int p = a; p < b; ++p) { if (firstp < 0) firstp = p; rpos[ptr++] = p; }
    }
    const int end = sBase[tid] + (((sCnt[tid] + 127) >> 7) << 7);
    for (; ptr < end; ++ptr) rpos[ptr] = (int)((unsigned)firstp | FLAGBIT);
  }
}

// ---- 8-phase gphase, 32x32x16 MFMA variant. Staging/vmcnt/barriers identical to r12.
//      Phase Q = m-frag (32 rows). A/B frag: row|col = lane&31, k = (lane>>5)*8+j.
template<int Q, bool LOADB, bool VMC>
__device__ __forceinline__ void gphase32(const char* LP,
    __attribute__((address_space(3))) char* LDS3,
    int rdBase, int aBase, int bBase, const int (&ch)[4],
    bf16x8 (&bfr)[2][4], f32x16 (&acc)[4][2],
    const unsigned short* s0, const unsigned short* s1, int d0, int d1)
{
  if constexpr (LOADB) {
#pragma unroll
    for (int nf = 0; nf < 2; ++nf)
#pragma unroll
      for (int ks = 0; ks < 4; ++ks)
        bfr[nf][ks] = *reinterpret_cast<const bf16x8*>(LP + rdBase + bBase + nf * 4096 + ch[ks]);
  }
  bf16x8 af[4];
#pragma unroll
  for (int ks = 0; ks < 4; ++ks)
    af[ks] = *reinterpret_cast<const bf16x8*>(LP + rdBase + aBase + Q * 4096 + ch[ks]);
  GLL(s0, LDS3 + d0);
  GLL(s1, LDS3 + d1);
  __builtin_amdgcn_sched_barrier(0);
  __builtin_amdgcn_s_barrier();
  __builtin_amdgcn_sched_barrier(0);
  __builtin_amdgcn_s_setprio(1);
#pragma unroll
  for (int ks = 0; ks < 4; ++ks)
#pragma unroll
    for (int nf = 0; nf < 2; ++nf)
      acc[Q][nf] = __builtin_amdgcn_mfma_f32_32x32x16_bf16(af[ks], bfr[nf][ks], acc[Q][nf], 0, 0, 0);
  __builtin_amdgcn_s_setprio(0);
  if constexpr (VMC) asm volatile("s_waitcnt vmcnt(4)" ::: "memory");
  __builtin_amdgcn_sched_barrier(0);
  __builtin_amdgcn_s_barrier();
  __builtin_amdgcn_sched_barrier(0);
}

// ---- merged: blocks <256 = main 256x256 GEMM (32x32x16); 256..767 = repair (16x16) ----
__global__ __launch_bounds__(512, 2) void k_gemm(const unsigned short* __restrict__ xb,
    const unsigned short* __restrict__ wb, const int* __restrict__ tlist,
    const int* __restrict__ estar, const int* __restrict__ mlo, const int* __restrict__ mhi,
    const int* __restrict__ rpos, const int* __restrict__ rtile, const int* __restrict__ rtc,
    float* __restrict__ out)
{
  __shared__ short lds[65536];  // 128 KiB
  const int bid = blockIdx.x;
  const int tid = threadIdx.x;
  const int l = tid & 63, wv = tid >> 6;
  const char* LP = (const char*)lds;
  auto* LDS3 = (__attribute__((address_space(3))) char*)lds;
  const int csrc = ((l & 7) ^ ((l >> 3) & 7)) * 8;
  const int srow = l >> 3;

  if (bid < 256) {
    const int mt = (bid & 7) * 4 + ((bid >> 3) & 3);  // XCD-locality map
    const int nt = bid >> 5;
    const int m0 = mt * 256, f0 = nt * 256;
    const int e = estar[mt], mLo = mlo[mt], mHi = mhi[mt];
    const int wm = wv >> 2, wn = wv & 3;   // 2M x 4N waves, 128x64 out each
    const int l31 = l & 31, hi = l >> 5, s7 = l & 7;

    // read addressing (32x32 frags): row|col = base + l31; k-chunk (16B) = 2*ks + hi,
    // stored at chunk ^ (row&7) = ^(l&7) (same involution as the staging side)
    int ch[4];
#pragma unroll
    for (int ks = 0; ks < 4; ++ks) ch[ks] = ((2 * ks + hi) ^ s7) << 4;
    const int aBase = (wm * 128 + l31) * 128;
    const int bBase = 32768 + (wn * 64 + l31) * 128;

    const unsigned short* aP[2][2];
    const unsigned short* bP[2][2];
    const unsigned short* wpan = wb + (size_t)e * H_DIM * H_DIM;
#pragma unroll
    for (int h = 0; h < 2; ++h)
#pragma unroll
      for (int j = 0; j < 2; ++j) {
        const int tok = tlist[m0 + h * 128 + (wv * 2 + j) * 8 + srow];
        aP[h][j] = xb + (size_t)tok * H_DIM + csrc;
        bP[h][j] = wpan + (size_t)(f0 + h * 128 + (wv * 2 + j) * 8 + srow) * H_DIM + csrc;
      }
    const int sl0 = wv * 2048, sl1 = wv * 2048 + 1024;

    f32x16 acc[4][2];
#pragma unroll
    for (int mf = 0; mf < 4; ++mf)
#pragma unroll
      for (int nf = 0; nf < 2; ++nf)
#pragma unroll
        for (int q = 0; q < 16; ++q) acc[mf][nf][q] = 0.f;
    bf16x8 bfr[2][4];

    GLL(aP[0][0], LDS3 + 0 + sl0);      GLL(aP[0][1], LDS3 + 0 + sl1);
    GLL(aP[1][0], LDS3 + 16384 + sl0);  GLL(aP[1][1], LDS3 + 16384 + sl1);
    GLL(bP[0][0], LDS3 + 32768 + sl0);  GLL(bP[0][1], LDS3 + 32768 + sl1);
    GLL(bP[1][0], LDS3 + 49152 + sl0);  GLL(bP[1][1], LDS3 + 49152 + sl1);
    GLL(bP[0][0] + 64, LDS3 + 65536 + 32768 + sl0);  GLL(bP[0][1] + 64, LDS3 + 65536 + 32768 + sl1);
    GLL(bP[1][0] + 64, LDS3 + 65536 + 49152 + sl0);  GLL(bP[1][1] + 64, LDS3 + 65536 + 49152 + sl1);
    asm volatile("s_waitcnt vmcnt(4)" ::: "memory");
    __builtin_amdgcn_sched_barrier(0);
    __builtin_amdgcn_s_barrier();
    __builtin_amdgcn_sched_barrier(0);

    for (int i = 0; i < 16; ++i) {
      const int kk1 = ((2 * i + 1) << 6) & (H_DIM - 1);
      const int kk2 = ((2 * i + 2) << 6) & (H_DIM - 1);
      const int kk3 = ((2 * i + 3) << 6) & (H_DIM - 1);
      gphase32<0, true , false>(LP, LDS3, 0, aBase, bBase, ch, bfr, acc,
          aP[0][0] + kk1, aP[0][1] + kk1, 65536 + 0 + sl0, 65536 + 0 + sl1);
      gphase32<1, false, false>(LP, LDS3, 0, aBase, bBase, ch, bfr, acc,
          aP[1][0] + kk1, aP[1][1] + kk1, 65536 + 16384 + sl0, 65536 + 16384 + sl1);
      gphase32<2, false, false>(LP, LDS3, 0, aBase, bBase, ch, bfr, acc,
          bP[0][0] + kk2, bP[0][1] + kk2, 0 + 32768 + sl0, 0 + 32768 + sl1);
      gphase32<3, false, true >(LP, LDS3, 0, aBase, bBase, ch, bfr, acc,
          bP[1][0] + kk2, bP[1][1] + kk2, 0 + 49152 + sl0, 0 + 49152 + sl1);
      gphase32<0, true , false>(LP, LDS3, 65536, aBase, bBase, ch, bfr, acc,
          aP[0][0] + kk2, aP[0][1] + kk2, 0 + 0 + sl0, 0 + 0 + sl1);
      gphase32<1, false, false>(LP, LDS3, 65536, aBase, bBase, ch, bfr, acc,
          aP[1][0] + kk2, aP[1][1] + kk2, 0 + 16384 + sl0, 0 + 16384 + sl1);
      gphase32<2, false, false>(LP, LDS3, 65536, aBase, bBase, ch, bfr, acc,
          bP[0][0] + kk3, bP[0][1] + kk3, 65536 + 32768 + sl0, 65536 + 32768 + sl1);
      gphase32<3, false, true >(LP, LDS3, 65536, aBase, bBase, ch, bfr, acc,
          bP[1][0] + kk3, bP[1][1] + kk3, 65536 + 49152 + sl0, 65536 + 49152 + sl1);
    }

    // epilogue: C/D map col = lane&31, row = (reg&3)+8*(reg>>2)+4*(lane>>5) [m74/m101]
#pragma unroll
    for (int mf = 0; mf < 4; ++mf) {
#pragma unroll
      for (int reg = 0; reg < 16; ++reg) {
        const int row = wm * 128 + mf * 32 + (reg & 3) + 8 * (reg >> 2) + 4 * hi;
        if (row >= mLo && row < mHi) {   // minority rows owned by repair blocks
          const int t = tlist[m0 + row];
          float* op = out + (size_t)t * H_DIM + f0 + wn * 64 + l31;
#pragma unroll
          for (int nf = 0; nf < 2; ++nf) op[nf * 32] = acc[mf][nf][reg];
        }
      }
    }
    return;
  }

  // ---------------- repair: 128x256 tile, full K, plain stores (r12, 16x16) ----------------
  const int l16 = l & 15, g = l >> 4;
  const int sw = l16 & 7;
  const int ch0 = ((0 + g) ^ sw) << 4;
  const int ch1 = ((4 + g) ^ sw) << 4;
  const int bid2 = bid - 256;
  const int bx = bid2 >> 3;
  if (bx >= *rtc) return;
  const int f0 = (bid2 & 7) * 256;
  const int e = rtile[bx];
  const int wm = wv >> 2, wn = wv & 3;

  const unsigned short* aS[2];
#pragma unroll
  for (int j = 0; j < 2; ++j) {
    const int ent = rpos[bx * 128 + (wv * 2 + j) * 8 + srow];
    const int tok = tlist[ent & 0x7fffffff];
    aS[j] = xb + (size_t)tok * H_DIM + csrc;
  }
  const unsigned short* bS[4];
#pragma unroll
  for (int j = 0; j < 4; ++j)
    bS[j] = wb + (size_t)e * H_DIM * H_DIM + (size_t)(f0 + (wv * 4 + j) * 8 + srow) * H_DIM + csrc;

  f32x4 acc[4][4];
#pragma unroll
  for (int mf = 0; mf < 4; ++mf)
#pragma unroll
    for (int nf = 0; nf < 4; ++nf) acc[mf][nf] = (f32x4){0.f, 0.f, 0.f, 0.f};

  for (int it = 0; it < 32; ++it) {
    const int kk = it * 64;
    __syncthreads();
#pragma unroll
    for (int j = 0; j < 2; ++j) GLL(aS[j] + kk, LDS3 + (wv * 2 + j) * 1024);
#pragma unroll
    for (int j = 0; j < 4; ++j) GLL(bS[j] + kk, LDS3 + 16384 + (wv * 4 + j) * 1024);
    __syncthreads();
    bf16x8 af[4][2];
#pragma unroll
    for (int mf = 0; mf < 4; ++mf) {
      af[mf][0] = *reinterpret_cast<const bf16x8*>(LP + (wm * 64 + mf * 16 + l16) * 128 + ch0);
      af[mf][1] = *reinterpret_cast<const bf16x8*>(LP + (wm * 64 + mf * 16 + l16) * 128 + ch1);
    }
#pragma unroll
    for (int nf = 0; nf < 4; ++nf) {
      const bf16x8 b0 = *reinterpret_cast<const bf16x8*>(LP + 16384 + (wn * 64 + nf * 16 + l16) * 128 + ch0);
      const bf16x8 b1 = *reinterpret_cast<const bf16x8*>(LP + 16384 + (wn * 64 + nf * 16 + l16) * 128 + ch1);
#pragma unroll
      for (int mf = 0; mf < 4; ++mf) {
        acc[mf][nf] = __builtin_amdgcn_mfma_f32_16x16x32_bf16(af[mf][0], b0, acc[mf][nf], 0, 0, 0);
        acc[mf][nf] = __builtin_amdgcn_mfma_f32_16x16x32_bf16(af[mf][1], b1, acc[mf][nf], 0, 0, 0);
      }
    }
  }
#pragma unroll
  for (int mf = 0; mf < 4; ++mf) {
#pragma unroll
    for (int r = 0; r < 4; ++r) {
      const int row = wm * 64 + mf * 16 + g * 4 + r;
      const int ent = rpos[bx * 128 + row];
      if (!((unsigned)ent & FLAGBIT)) {
        const int tok = tlist[ent];
        float* op = out + (size_t)tok * H_DIM + f0 + wn * 64 + l16;
#pragma unroll
        for (int nf = 0; nf < 4; ++nf) op[nf * 16] = acc[mf][nf][r];
      }
    }
  }
}

extern "C" void kernel_launch(void* const* d_in, const int* in_sizes, int n_in,
                              void* d_out, int out_size, void* d_ws, size_t ws_size,
                              hipStream_t stream) {
  const float* x  = (const float*)d_in[0];
  const float* wr = (const float*)d_in[1];
  const float* we = (const float*)d_in[2];
  float* out = (float*)d_out;

  char* p = (char*)d_ws;
  unsigned short* xb = (unsigned short*)p; p += (size_t)T_TOK * H_DIM * 2;          // 32 MB
  unsigned short* wb = (unsigned short*)p; p += (size_t)N_EXP * H_DIM * H_DIM * 2;  // 64 MB
  int* idx    = (int*)p; p += T_TOK * 4;
  int* tlist  = (int*)p; p += T_TOK * 4;
  int* rpos   = (int*)p; p += T_TOK * 4;
  int* estar  = (int*)p; p += 32 * 4;
  int* mlo    = (int*)p; p += 32 * 4;
  int* mhi    = (int*)p; p += 32 * 4;
  int* rtile  = (int*)p; p += 64 * 4;
  int* rtc    = (int*)p; p += 64;

  k_conv<<<2048, 256, 0, stream>>>(we, wb);
  k_router<<<512, 256, 0, stream>>>(x, wr, xb, idx);
  k_sort<<<1, 1024, 0, stream>>>(idx, tlist, estar, mlo, mhi, rpos, rtile, rtc);
  k_gemm<<<768, 512, 0, stream>>>(xb, wb, tlist, estar, mlo, mhi, rpos, rtile, rtc, out);
}

// Round 15
// 194.069 us; speedup vs baseline: 1.0943x; 1.0837x over previous
//
#include <hip/hip_runtime.h>
#include <hip/hip_bf16.h>
#include <cstdint>

#define T_TOK 8192
#define H_DIM 2048
#define N_EXP 8
#define FLAGBIT 0x80000000u

typedef __attribute__((ext_vector_type(4))) float f32x4;
typedef __attribute__((ext_vector_type(8))) short bf16x8;

__device__ __forceinline__ unsigned short f2bf(float f) {
  unsigned int u = __builtin_bit_cast(unsigned int, f);
  u += 0x7fffu + ((u >> 16) & 1u);  // RNE
  return (unsigned short)(u >> 16);
}

#define GLL(SRC, DST) __builtin_amdgcn_global_load_lds( \
    (const __attribute__((address_space(1))) void*)(SRC), \
    (__attribute__((address_space(3))) void*)(DST), 16, 0, 0)

// ---- conv: W f32->bf16 (r12: forced 16-deep load pipeline) ----
__global__ __launch_bounds__(256, 2) void k_conv(const float* __restrict__ we,
                                                 unsigned short* __restrict__ wb) {
  const size_t tix = ((size_t)blockIdx.x * 256 + threadIdx.x) * 8;
  const size_t stride = (size_t)2048 * 256 * 8;
  f32x4 v[16];
#pragma unroll
  for (int it = 0; it < 8; ++it) {
    v[2 * it]     = *reinterpret_cast<const f32x4*>(we + tix + (size_t)it * stride);
    v[2 * it + 1] = *reinterpret_cast<const f32x4*>(we + tix + (size_t)it * stride + 4);
  }
#pragma unroll
  for (int q = 0; q < 16; ++q) asm volatile("" : "+v"(v[q]));
#pragma unroll
  for (int it = 0; it < 8; ++it) {
    union { unsigned short h[8]; uint4 u; } r;
#pragma unroll
    for (int q = 0; q < 4; ++q) {
      r.h[q]     = f2bf(v[2 * it][q]);
      r.h[4 + q] = f2bf(v[2 * it + 1][q]);
    }
    *reinterpret_cast<uint4*>(wb + tix + (size_t)it * stride) = r.u;
  }
}

// ---- router: wr in LDS, 4 tok/wave, atomic-free (r12) ----
__global__ __launch_bounds__(256) void k_router(const float* __restrict__ x,
    const float* __restrict__ wr, unsigned short* __restrict__ xb,
    int* __restrict__ idx)
{
  __shared__ float swr[N_EXP * H_DIM];  // 64 KB
#pragma unroll
  for (int i = 0; i < 16; ++i) {
    const int o = (threadIdx.x + i * 256) * 4;
    *reinterpret_cast<float4*>(&swr[o]) = *reinterpret_cast<const float4*>(&wr[o]);
  }
  __syncthreads();
  const int wv = threadIdx.x >> 6, lane = threadIdx.x & 63;
  const int t0 = (blockIdx.x * 4 + wv) * 4;
  float acc[4][N_EXP];
#pragma unroll
  for (int tt = 0; tt < 4; ++tt)
#pragma unroll
    for (int e = 0; e < N_EXP; ++e) acc[tt][e] = 0.f;
#pragma unroll
  for (int c = 0; c < H_DIM / 256; ++c) {
    const int h = c * 256 + lane * 4;
    float4 wvv[N_EXP];
#pragma unroll
    for (int e = 0; e < N_EXP; ++e)
      wvv[e] = *reinterpret_cast<const float4*>(&swr[e * H_DIM + h]);
#pragma unroll
    for (int tt = 0; tt < 4; ++tt) {
      const float4 xv = *reinterpret_cast<const float4*>(x + (size_t)(t0 + tt) * H_DIM + h);
      ushort4 bv;
      bv.x = f2bf(xv.x); bv.y = f2bf(xv.y); bv.z = f2bf(xv.z); bv.w = f2bf(xv.w);
      *reinterpret_cast<ushort4*>(xb + (size_t)(t0 + tt) * H_DIM + h) = bv;
#pragma unroll
      for (int e = 0; e < N_EXP; ++e) {
        acc[tt][e] = fmaf(xv.x, wvv[e].x, acc[tt][e]);
        acc[tt][e] = fmaf(xv.y, wvv[e].y, acc[tt][e]);
        acc[tt][e] = fmaf(xv.z, wvv[e].z, acc[tt][e]);
        acc[tt][e] = fmaf(xv.w, wvv[e].w, acc[tt][e]);
      }
    }
  }
#pragma unroll
  for (int off = 32; off >= 1; off >>= 1)
#pragma unroll
    for (int tt = 0; tt < 4; ++tt)
#pragma unroll
      for (int e = 0; e < N_EXP; ++e) acc[tt][e] += __shfl_xor(acc[tt][e], off, 64);
  if (lane == 0) {
#pragma unroll
    for (int tt = 0; tt < 4; ++tt) {
      float best = acc[tt][0]; int be = 0;
#pragma unroll
      for (int e = 1; e < N_EXP; ++e) if (acc[tt][e] > best) { best = acc[tt][e]; be = e; }
      idx[t0 + tt] = be;
    }
  }
}

// ---- fused sort (r11) ----
__global__ __launch_bounds__(1024) void k_sort(const int* __restrict__ idx,
    int* __restrict__ tlist, int* __restrict__ estar, int* __restrict__ mlo,
    int* __restrict__ mhi, int* __restrict__ rpos, int* __restrict__ rtile,
    int* __restrict__ rtc)
{
  __shared__ int wc[N_EXP][128];
  __shared__ int wbase[N_EXP][128];
  __shared__ int sTot[N_EXP];
  __shared__ int off[N_EXP + 1];
  __shared__ int sE[32], sCnt[N_EXP], sBase[N_EXP];
  const int tid = threadIdx.x, w = tid >> 6, l = tid & 63;
  int myE[8];
#pragma unroll
  for (int j = 0; j < 8; ++j) {
    myE[j] = idx[j * 1024 + tid];
#pragma unroll
    for (int e = 0; e < N_EXP; ++e) {
      const unsigned long long bm = __ballot(myE[j] == e);
      if (l == e) wc[e][j * 16 + w] = __popcll(bm);
    }
  }
  __syncthreads();
  if (tid < N_EXP) {
    int s = 0;
    for (int k = 0; k < 128; ++k) { wbase[tid][k] = s; s += wc[tid][k]; }
    sTot[tid] = s;
  }
  __syncthreads();
  if (tid == 0) {
    off[0] = 0;
    for (int e = 0; e < N_EXP; ++e) off[e + 1] = off[e] + sTot[e];
  }
  __syncthreads();
#pragma unroll
  for (int j = 0; j < 8; ++j) {
    int rank = 0;
#pragma unroll
    for (int e = 0; e < N_EXP; ++e) {
      const unsigned long long bm = __ballot(myE[j] == e);
      if (myE[j] == e) rank = __popcll(bm & ((1ull << l) - 1ull));
    }
    tlist[off[myE[j]] + wbase[myE[j]][j * 16 + w] + rank] = j * 1024 + tid;
  }
  if (tid < 32) {
    const int lo = tid * 256, hi = lo + 256;
    int bl = -1, bE = 0, bLo = 0, bHi = 0;
#pragma unroll
    for (int e = 0; e < N_EXP; ++e) {
      const int a = off[e] > lo ? off[e] : lo;
      const int b = off[e + 1] < hi ? off[e + 1] : hi;
      if (b - a > bl) { bl = b - a; bE = e; bLo = a - lo; bHi = b - lo; }
    }
    sE[tid] = bE; estar[tid] = bE; mlo[tid] = bLo; mhi[tid] = bHi;
  }
  __syncthreads();
  if (tid < N_EXP) {
    int cnt = 0;
    for (int t = 0; t < 32; ++t) {
      if (sE[t] == tid) continue;
      const int lo = t * 256, hi = lo + 256;
      const int a = off[tid] > lo ? off[tid] : lo;
      const int b = off[tid + 1] < hi ? off[tid + 1] : hi;
      if (b > a) cnt += b - a;
    }
    sCnt[tid] = cnt;
  }
  __syncthreads();
  if (tid == 0) {
    int base = 0, ntile = 0;
    for (int e = 0; e < N_EXP; ++e) {
      sBase[e] = base;
      const int pt = (sCnt[e] + 127) >> 7;
      for (int k = 0; k < pt; ++k) rtile[ntile++] = e;
      base += pt << 7;
    }
    *rtc = ntile;
  }
  __syncthreads();
  if (tid < N_EXP && sCnt[tid] > 0) {
    int ptr = sBase[tid], firstp = -1;
    for (int t = 0; t < 32; ++t) {
      if (sE[t] == tid) continue;
      const int lo = t * 256, hi = lo + 256;
      const int a = off[tid] > lo ? off[tid] : lo;
      const int b = off[tid + 1] < hi ? off[tid + 1] : hi;
      for (int p = a; p < b; ++p) { if (firstp < 0) firstp = p; rpos[ptr++] = p; }
    }
    const int end = sBase[tid] + (((sCnt[tid] + 127) >> 7) << 7);
    for (; ptr < end; ++ptr) rpos[ptr] = (int)((unsigned)firstp | FLAGBIT);
  }
}

// ---- zero minority cells (atomicAdd base for split-K repair); ~2.5 MB writes ----
__global__ __launch_bounds__(256) void k_zero_min(const int* __restrict__ rpos,
    const int* __restrict__ tlist, const int* __restrict__ rtc,
    float* __restrict__ out)
{
  const int nslots = (*rtc) << 7;
  const float4 z = {0.f, 0.f, 0.f, 0.f};
  for (int s = blockIdx.x; s < nslots; s += 256) {
    const int ent = rpos[s];
    if ((unsigned)ent & FLAGBIT) continue;   // uniform per block
    const int tok = tlist[ent];
    float* op = out + (size_t)tok * H_DIM;
    for (int i = threadIdx.x; i < H_DIM / 4; i += 256)
      reinterpret_cast<float4*>(op)[i] = z;
  }
}

// ---- r12 8-phase gphase (bf16 wb, GLL both operands, counted vmcnt) ----
// NOTE: vmcnt(4) at p3/p7 nominally leaves A(t1) outstanding; correctness is
// carried by the 4-phase (~2800 cy) issue->consume lead > 900 cy HBM latency.
template<int Q, bool LOADB, bool VMC>
__device__ __forceinline__ void gphase(const char* LP,
    __attribute__((address_space(3))) char* LDS3,
    int rdBase, int aRowOff, int bRowOff, int ch0, int ch1,
    bf16x8 (&bfr)[8], f32x4 (&acc)[8][4],
    const unsigned short* s0, const unsigned short* s1, int d0, int d1)
{
  if constexpr (LOADB) {
#pragma unroll
    for (int nf = 0; nf < 4; ++nf) {
      bfr[nf * 2 + 0] = *reinterpret_cast<const bf16x8*>(LP + rdBase + 32768 + bRowOff + nf * 2048 + ch0);
      bfr[nf * 2 + 1] = *reinterpret_cast<const bf16x8*>(LP + rdBase + 32768 + bRowOff + nf * 2048 + ch1);
    }
  }
  bf16x8 af[2][2];
#pragma unroll
  for (int m = 0; m < 2; ++m) {
    af[m][0] = *reinterpret_cast<const bf16x8*>(LP + rdBase + aRowOff + (2 * Q + m) * 2048 + ch0);
    af[m][1] = *reinterpret_cast<const bf16x8*>(LP + rdBase + aRowOff + (2 * Q + m) * 2048 + ch1);
  }
  GLL(s0, LDS3 + d0);
  GLL(s1, LDS3 + d1);
  __builtin_amdgcn_sched_barrier(0);
  __builtin_amdgcn_s_barrier();
  __builtin_amdgcn_sched_barrier(0);
  __builtin_amdgcn_s_setprio(1);
#pragma unroll
  for (int ks = 0; ks < 2; ++ks)
#pragma unroll
    for (int m = 0; m < 2; ++m)
#pragma unroll
      for (int nf = 0; nf < 4; ++nf)
        acc[2 * Q + m][nf] = __builtin_amdgcn_mfma_f32_16x16x32_bf16(af[m][ks], bfr[nf * 2 + ks], acc[2 * Q + m][nf], 0, 0, 0);
  __builtin_amdgcn_s_setprio(0);
  if constexpr (VMC) asm volatile("s_waitcnt vmcnt(4)" ::: "memory");
  __builtin_amdgcn_sched_barrier(0);
  __builtin_amdgcn_s_barrier();
  __builtin_amdgcn_sched_barrier(0);
}

// ---- merged: blocks <256 = main 256x256 GEMM (skip minority rows);
//      blocks 256..1279 = repair (split-K(2), atomicAdd onto zeroed cells) ----
__global__ __launch_bounds__(512, 2) void k_gemm(const unsigned short* __restrict__ xb,
    const unsigned short* __restrict__ wb, const int* __restrict__ tlist,
    const int* __restrict__ estar, const int* __restrict__ mlo, const int* __restrict__ mhi,
    const int* __restrict__ rpos, const int* __restrict__ rtile, const int* __restrict__ rtc,
    float* __restrict__ out)
{
  __shared__ short lds[65536];  // 128 KiB
  const int bid = blockIdx.x;
  const int tid = threadIdx.x;
  const int l = tid & 63, wv = tid >> 6;
  const int l16 = l & 15, g = l >> 4;
  const char* LP = (const char*)lds;
  auto* LDS3 = (__attribute__((address_space(3))) char*)lds;
  const int sw = l16 & 7;
  const int ch0 = ((0 + g) ^ sw) << 4;
  const int ch1 = ((4 + g) ^ sw) << 4;
  const int csrc = ((l & 7) ^ ((l >> 3) & 7)) * 8;
  const int srow = l >> 3;

  if (bid < 256) {
    const int mt = (bid & 7) * 4 + ((bid >> 3) & 3);  // XCD-locality map
    const int nt = bid >> 5;
    const int m0 = mt * 256, f0 = nt * 256;
    const int e = estar[mt], mLo = mlo[mt], mHi = mhi[mt];
    const int wm = wv >> 2, wn = wv & 3;
    const int aRowOff = (wm * 128 + l16) * 128;
    const int bRowOff = (wn * 64 + l16) * 128;

    const unsigned short* aP[2][2];
    const unsigned short* bP[2][2];
    const unsigned short* wpan = wb + (size_t)e * H_DIM * H_DIM;
#pragma unroll
    for (int h = 0; h < 2; ++h)
#pragma unroll
      for (int j = 0; j < 2; ++j) {
        const int tok = tlist[m0 + h * 128 + (wv * 2 + j) * 8 + srow];
        aP[h][j] = xb + (size_t)tok * H_DIM + csrc;
        bP[h][j] = wpan + (size_t)(f0 + h * 128 + (wv * 2 + j) * 8 + srow) * H_DIM + csrc;
      }
    const int sl0 = wv * 2048, sl1 = wv * 2048 + 1024;

    f32x4 acc[8][4];
#pragma unroll
    for (int mf = 0; mf < 8; ++mf)
#pragma unroll
      for (int nf = 0; nf < 4; ++nf) acc[mf][nf] = (f32x4){0.f, 0.f, 0.f, 0.f};
    bf16x8 bfr[8];

    GLL(aP[0][0], LDS3 + 0 + sl0);      GLL(aP[0][1], LDS3 + 0 + sl1);
    GLL(aP[1][0], LDS3 + 16384 + sl0);  GLL(aP[1][1], LDS3 + 16384 + sl1);
    GLL(bP[0][0], LDS3 + 32768 + sl0);  GLL(bP[0][1], LDS3 + 32768 + sl1);
    GLL(bP[1][0], LDS3 + 49152 + sl0);  GLL(bP[1][1], LDS3 + 49152 + sl1);
    GLL(bP[0][0] + 64, LDS3 + 65536 + 32768 + sl0);  GLL(bP[0][1] + 64, LDS3 + 65536 + 32768 + sl1);
    GLL(bP[1][0] + 64, LDS3 + 65536 + 49152 + sl0);  GLL(bP[1][1] + 64, LDS3 + 65536 + 49152 + sl1);
    asm volatile("s_waitcnt vmcnt(4)" ::: "memory");
    __builtin_amdgcn_sched_barrier(0);
    __builtin_amdgcn_s_barrier();
    __builtin_amdgcn_sched_barrier(0);

    for (int i = 0; i < 16; ++i) {
      const int kk1 = ((2 * i + 1) << 6) & (H_DIM - 1);
      const int kk2 = ((2 * i + 2) << 6) & (H_DIM - 1);
      const int kk3 = ((2 * i + 3) << 6) & (H_DIM - 1);
      gphase<0, true , false>(LP, LDS3, 0, aRowOff, bRowOff, ch0, ch1, bfr, acc,
          aP[0][0] + kk1, aP[0][1] + kk1, 65536 + 0 + sl0, 65536 + 0 + sl1);
      gphase<1, false, false>(LP, LDS3, 0, aRowOff, bRowOff, ch0, ch1, bfr, acc,
          aP[1][0] + kk1, aP[1][1] + kk1, 65536 + 16384 + sl0, 65536 + 16384 + sl1);
      gphase<2, false, false>(LP, LDS3, 0, aRowOff, bRowOff, ch0, ch1, bfr, acc,
          bP[0][0] + kk2, bP[0][1] + kk2, 0 + 32768 + sl0, 0 + 32768 + sl1);
      gphase<3, false, true >(LP, LDS3, 0, aRowOff, bRowOff, ch0, ch1, bfr, acc,
          bP[1][0] + kk2, bP[1][1] + kk2, 0 + 49152 + sl0, 0 + 49152 + sl1);
      gphase<0, true , false>(LP, LDS3, 65536, aRowOff, bRowOff, ch0, ch1, bfr, acc,
          aP[0][0] + kk2, aP[0][1] + kk2, 0 + 0 + sl0, 0 + 0 + sl1);
      gphase<1, false, false>(LP, LDS3, 65536, aRowOff, bRowOff, ch0, ch1, bfr, acc,
          aP[1][0] + kk2, aP[1][1] + kk2, 0 + 16384 + sl0, 0 + 16384 + sl1);
      gphase<2, false, false>(LP, LDS3, 65536, aRowOff, bRowOff, ch0, ch1, bfr, acc,
          bP[0][0] + kk3, bP[0][1] + kk3, 65536 + 32768 + sl0, 65536 + 32768 + sl1);
      gphase<3, false, true >(LP, LDS3, 65536, aRowOff, bRowOff, ch0, ch1, bfr, acc,
          bP[1][0] + kk3, bP[1][1] + kk3, 65536 + 49152 + sl0, 65536 + 49152 + sl1);
    }

#pragma unroll
    for (int mf = 0; mf < 8; ++mf) {
#pragma unroll
      for (int r = 0; r < 4; ++r) {
        const int row = wm * 128 + mf * 16 + g * 4 + r;
        if (row >= mLo && row < mHi) {   // minority cells zeroed by k_zero_min, added by repair
          const int t = tlist[m0 + row];
          float* op = out + (size_t)t * H_DIM + f0 + wn * 64 + l16;
#pragma unroll
          for (int nf = 0; nf < 4; ++nf) op[nf * 16] = acc[mf][nf][r];
        }
      }
    }
    return;
  }

  // ---------------- repair: 128x256 tile, split-K(2), atomicAdd ----------------
  const int bid2 = bid - 256;            // [0,1024)
  const int bx = bid2 >> 4;              // 64 repair tiles
  if (bx >= *rtc) return;
  const int f0 = ((bid2 >> 1) & 7) * 256;
  const int kc = bid2 & 1;
  const int e = rtile[bx];
  const int wm = wv >> 2, wn = wv & 3;   // 2M x 4N waves, 64x64 out each

  const unsigned short* aS[2];
#pragma unroll
  for (int j = 0; j < 2; ++j) {
    const int ent = rpos[bx * 128 + (wv * 2 + j) * 8 + srow];
    const int tok = tlist[ent & 0x7fffffff];
    aS[j] = xb + (size_t)tok * H_DIM + csrc;
  }
  const unsigned short* bS[4];
#pragma unroll
  for (int j = 0; j < 4; ++j)
    bS[j] = wb + (size_t)e * H_DIM * H_DIM + (size_t)(f0 + (wv * 4 + j) * 8 + srow) * H_DIM + csrc;

  f32x4 acc[4][4];
#pragma unroll
  for (int mf = 0; mf < 4; ++mf)
#pragma unroll
    for (int nf = 0; nf < 4; ++nf) acc[mf][nf] = (f32x4){0.f, 0.f, 0.f, 0.f};

  for (int it = 0; it < 16; ++it) {
    const int kk = kc * 1024 + it * 64;
    __syncthreads();
#pragma unroll
    for (int j = 0; j < 2; ++j) GLL(aS[j] + kk, LDS3 + (wv * 2 + j) * 1024);
#pragma unroll
    for (int j = 0; j < 4; ++j) GLL(bS[j] + kk, LDS3 + 16384 + (wv * 4 + j) * 1024);
    __syncthreads();
    bf16x8 af[4][2];
#pragma unroll
    for (int mf = 0; mf < 4; ++mf) {
      af[mf][0] = *reinterpret_cast<const bf16x8*>(LP + (wm * 64 + mf * 16 + l16) * 128 + ch0);
      af[mf][1] = *reinterpret_cast<const bf16x8*>(LP + (wm * 64 + mf * 16 + l16) * 128 + ch1);
    }
#pragma unroll
    for (int nf = 0; nf < 4; ++nf) {
      const bf16x8 b0 = *reinterpret_cast<const bf16x8*>(LP + 16384 + (wn * 64 + nf * 16 + l16) * 128 + ch0);
      const bf16x8 b1 = *reinterpret_cast<const bf16x8*>(LP + 16384 + (wn * 64 + nf * 16 + l16) * 128 + ch1);
#pragma unroll
      for (int mf = 0; mf < 4; ++mf) {
        acc[mf][nf] = __builtin_amdgcn_mfma_f32_16x16x32_bf16(af[mf][0], b0, acc[mf][nf], 0, 0, 0);
        acc[mf][nf] = __builtin_amdgcn_mfma_f32_16x16x32_bf16(af[mf][1], b1, acc[mf][nf], 0, 0, 0);
      }
    }
  }
#pragma unroll
  for (int mf = 0; mf < 4; ++mf) {
#pragma unroll
    for (int r = 0; r < 4; ++r) {
      const int row = wm * 64 + mf * 16 + g * 4 + r;
      const int ent = rpos[bx * 128 + row];
      if (!((unsigned)ent & FLAGBIT)) {
        const int tok = tlist[ent];
        float* op = out + (size_t)tok * H_DIM + f0 + wn * 64 + l16;
#pragma unroll
        for (int nf = 0; nf < 4; ++nf) atomicAdd(op + nf * 16, acc[mf][nf][r]);
      }
    }
  }
}

extern "C" void kernel_launch(void* const* d_in, const int* in_sizes, int n_in,
                              void* d_out, int out_size, void* d_ws, size_t ws_size,
                              hipStream_t stream) {
  const float* x  = (const float*)d_in[0];
  const float* wr = (const float*)d_in[1];
  const float* we = (const float*)d_in[2];
  float* out = (float*)d_out;

  char* p = (char*)d_ws;
  unsigned short* xb = (unsigned short*)p; p += (size_t)T_TOK * H_DIM * 2;          // 32 MB
  unsigned short* wb = (unsigned short*)p; p += (size_t)N_EXP * H_DIM * H_DIM * 2;  // 64 MB
  int* idx    = (int*)p; p += T_TOK * 4;
  int* tlist  = (int*)p; p += T_TOK * 4;
  int* rpos   = (int*)p; p += T_TOK * 4;
  int* estar  = (int*)p; p += 32 * 4;
  int* mlo    = (int*)p; p += 32 * 4;
  int* mhi    = (int*)p; p += 32 * 4;
  int* rtile  = (int*)p; p += 64 * 4;
  int* rtc    = (int*)p; p += 64;

  k_conv<<<2048, 256, 0, stream>>>(we, wb);
  k_router<<<512, 256, 0, stream>>>(x, wr, xb, idx);
  k_sort<<<1, 1024, 0, stream>>>(idx, tlist, estar, mlo, mhi, rpos, rtile, rtc);
  k_zero_min<<<256, 256, 0, stream>>>(rpos, tlist, rtc, out);
  k_gemm<<<256 + 1024, 512, 0, stream>>>(xb, wb, tlist, estar, mlo, mhi, rpos, rtile, rtc, out);
}